// Round 5
// baseline (714.720 us; speedup 1.0000x reference)
//
#include <hip/hip_runtime.h>
#include <hip/hip_cooperative_groups.h>

namespace cg = cooperative_groups;

// LinearMemoryBackend: y_t = M_t q_t, M_t = sum_{s<=t} v_s k_s^T
// Fused cooperative version (1024 blocks co-resident, 2 grid syncs):
//  phase1: S_c = sum_t v k^T (bf16 MFMA), Q/K/V tiles persist in LDS
//  phase2: exclusive prefix over chunks; M stored as packed bf16 hi|lo u32
//  phase3: y = (QK^T masked)V + Q*M  (M B-frags straight from global)
// Fallback: previous 3-kernel pipeline if cooperative launch fails.

#define B_   2
#define T_   4096
#define H_   8
#define D_   64
#define CH   64
#define NC   (T_ / CH)
#define BH   (B_ * H_)
#define SROW (H_ * D_)
#define SB   (T_ * H_ * D_)

typedef __attribute__((ext_vector_type(4))) float f32x4;
typedef __attribute__((ext_vector_type(8))) short bf16x8;

__device__ inline unsigned short f2bf(float f) {
  unsigned int u = __builtin_bit_cast(unsigned int, f);
  unsigned int r = (u + 0x7FFFu + ((u >> 16) & 1u)) >> 16;
  return (unsigned short)r;
}
__device__ inline float bf2f(unsigned short b) {
  unsigned int u = ((unsigned int)b) << 16;
  return __builtin_bit_cast(float, u);
}
__device__ inline void st4bf(unsigned short* p, float a, float b, float c, float d) {
  union { uint2 u; unsigned short s[4]; } x;
  x.s[0] = f2bf(a); x.s[1] = f2bf(b); x.s[2] = f2bf(c); x.s[3] = f2bf(d);
  *(uint2*)p = x.u;
}
__device__ inline bf16x8 ld128(const unsigned short* p) {
  union { uint4 u; bf16x8 v; } x;
  x.u = *(const uint4*)p;
  return x.v;
}
__device__ inline void unpackM(const uint4 a, const uint4 b, bf16x8& hi, bf16x8& lo) {
  unsigned xs[8] = { a.x, a.y, a.z, a.w, b.x, b.y, b.z, b.w };
  union { unsigned u[4]; bf16x8 v; } H, L;
#pragma unroll
  for (int i = 0; i < 4; ++i) {
    unsigned p0 = xs[2 * i], p1 = xs[2 * i + 1];
    H.u[i] = (p0 >> 16) | (p1 & 0xffff0000u);
    L.u[i] = (p0 & 0xffffu) | (p1 << 16);
  }
  hi = H.v; lo = L.v;
}

// ================= fused cooperative kernel =================
__global__ __launch_bounds__(256, 4) void k_fused(const float* __restrict__ qp,
                                                  const float* __restrict__ kp,
                                                  const float* __restrict__ vp,
                                                  float* __restrict__ Wp,
                                                  float* __restrict__ yp) {
  // 4 x 8KB buffers = 32768 B -> 4 blocks/CU guaranteed.
  // QF,KF,VH persist phase1->phase3. SCR: p1 = K^T hi, p2 = partial-sum
  // exchange, p3 = P round-trip (octet layout).
  __shared__ __align__(16) unsigned short QF[4096], KF[4096], VH[4096], SCR[4096];

  const int bid = blockIdx.x;
  const int c   = bid & 63;      // NC = 64
  const int bh  = bid >> 6;
  const int b   = bh >> 3, h = bh & 7;
  const size_t base = (size_t)b * SB + (size_t)h * D_ + (size_t)(c * CH) * SROW;

  const int tid = threadIdx.x;
  const int l = tid & 63, w = tid >> 6;
  const int mlan = l & 15, qlan = l >> 4;
  const int rslot = ((mlan & 3) << 4) + (qlan << 2) + (mlan >> 2);

  cg::grid_group grid = cg::this_grid();

  // ---------- phase 1: stage + chunk sums ----------
  // (a) Q,K row-form (A/B-frag order)
#pragma unroll
  for (int it = 0; it < 4; ++it) {
    const int f = tid + it * 256;
    const int t = f >> 4, m0 = f & 15;
    const int kb = m0 >> 3, qq = (m0 & 7) >> 1, j0 = (m0 & 1) * 4;
    const int addr = (((t >> 4) * 2 + kb) * 64 + ((t & 15) * 4 + qq)) * 8 + j0;
    const size_t g = base + (size_t)t * SROW + 4 * m0;
    float4 qv = *(const float4*)(qp + g);
    float4 kv = *(const float4*)(kp + g);
    st4bf(QF + addr, qv.x, qv.y, qv.z, qv.w);
    st4bf(KF + addr, kv.x, kv.y, kv.z, kv.w);
  }
  // (b) K^T -> SCR, V^T -> VH (transposed staging, bf16)
  {
    const int t0 = (tid >> 4) * 4;
    const int m0 = tid & 15;
    const int qs = (t0 >> 3) & 3, kbs = t0 >> 5, j0 = t0 & 4;
    float4 kr[4], vr[4];
#pragma unroll
    for (int i = 0; i < 4; ++i) {
      const size_t g = base + (size_t)(t0 + i) * SROW + 4 * m0;
      kr[i] = *(const float4*)(kp + g);
      vr[i] = *(const float4*)(vp + g);
    }
#pragma unroll
    for (int r = 0; r < 4; ++r) {
      const int d = 4 * m0 + r;
      const int slot = r * 16 + qs * 4 + (m0 & 3);
      const int addr = (((d >> 4) * 2 + kbs) * 64 + slot) * 8 + j0;
      st4bf(SCR + addr, ((const float*)&kr[0])[r], ((const float*)&kr[1])[r],
                        ((const float*)&kr[2])[r], ((const float*)&kr[3])[r]);
      st4bf(VH + addr,  ((const float*)&vr[0])[r], ((const float*)&vr[1])[r],
                        ((const float*)&vr[2])[r], ((const float*)&vr[3])[r]);
    }
  }
  __syncthreads();

  {
    bf16x8 av[2];
    av[0] = ld128(VH + ((w * 2 + 0) * 64 + rslot) * 8);
    av[1] = ld128(VH + ((w * 2 + 1) * 64 + rslot) * 8);
    float* Wc = Wp + (size_t)bid * 4096;
#pragma unroll
    for (int te = 0; te < 4; ++te) {
      f32x4 acc = {0.f, 0.f, 0.f, 0.f};
#pragma unroll
      for (int kb = 0; kb < 2; ++kb) {
        bf16x8 bk = ld128(SCR + ((te * 2 + kb) * 64 + rslot) * 8);
        acc = __builtin_amdgcn_mfma_f32_16x16x32_bf16(av[kb], bk, acc, 0, 0, 0);
      }
#pragma unroll
      for (int r = 0; r < 4; ++r)
        Wc[(16 * w + 4 * qlan + r) * 64 + 16 * te + mlan] = acc[r];
    }
  }
  __threadfence();
  grid.sync();
  __threadfence();

  // ---------- phase 2: exclusive prefix, packed bf16 hi|lo output ----------
  {
    // block covers one bh (bid>>6) and 64 e-columns (bid&63); wave index = chunk quarter
    unsigned* colp = (unsigned*)Wp + (size_t)(bid >> 6) * (NC * 4096)
                   + (size_t)(bid & 63) * 64 + l + (size_t)w * 16 * 4096;
    float vb[16];
#pragma unroll
    for (int i = 0; i < 16; ++i)
      vb[i] = __builtin_bit_cast(float, colp[(size_t)i * 4096]);
    float s = 0.f;
#pragma unroll
    for (int i = 0; i < 16; ++i) s += vb[i];
    float* xch = (float*)SCR;
    xch[tid] = s;
    __syncthreads();
    float run = 0.f;
    for (int j = 0; j < w; ++j) run += xch[j * 64 + l];
#pragma unroll
    for (int i = 0; i < 16; ++i) {
      unsigned short hi = f2bf(run);
      float lo = run - bf2f(hi);
      colp[(size_t)i * 4096] = ((unsigned)hi << 16) | (unsigned)f2bf(lo);
      run += vb[i];
    }
  }
  __threadfence();
  grid.sync();
  __threadfence();

  // ---------- phase 3: y = (QK^T masked)V + Q*M ----------
  // prefetch M B-frags (packed u32) from global early
  uint4 mA[8], mB[8];
#pragma unroll
  for (int td = 0; td < 4; ++td)
#pragma unroll
    for (int kb = 0; kb < 2; ++kb) {
      const uint4* mp = (const uint4*)((const unsigned*)Wp + (size_t)bid * 4096
                                       + (16 * td + mlan) * 64 + 32 * kb + 8 * qlan);
      mA[td * 2 + kb] = mp[0];
      mB[td * 2 + kb] = mp[1];
    }

  bf16x8 aq[2];
#pragma unroll
  for (int kb = 0; kb < 2; ++kb)
    aq[kb] = ld128(QF + ((w * 2 + kb) * 64 + (mlan * 4 + qlan)) * 8);

  // matmul1: P = Q K^T (causal tiles only)
  f32x4 accP[4];
#pragma unroll
  for (int ts = 0; ts < 4; ++ts) accP[ts] = (f32x4){0.f, 0.f, 0.f, 0.f};
#pragma unroll
  for (int ts = 0; ts < 4; ++ts) {
    if (ts <= w) {
#pragma unroll
      for (int kb = 0; kb < 2; ++kb) {
        bf16x8 bk = ld128(KF + ((ts * 2 + kb) * 64 + (mlan * 4 + qlan)) * 8);
        accP[ts] = __builtin_amdgcn_mfma_f32_16x16x32_bf16(aq[kb], bk, accP[ts], 0, 0, 0);
      }
    }
  }
  // diagonal mask (keep s<=t)
#pragma unroll
  for (int ts = 0; ts < 4; ++ts)
    if (ts == w) {
#pragma unroll
      for (int r = 0; r < 4; ++r)
        if (mlan > qlan * 4 + r) accP[ts][r] = 0.f;
    }

  // P strip -> SCR in octet layout (wave-private 1024-short region):
  // element (row', col) at ((col>>3)*16 + row')*8 + (col&7)
  {
    unsigned short* PSW = SCR + w * 1024;
#pragma unroll
    for (int ts = 0; ts < 4; ++ts)
#pragma unroll
      for (int r = 0; r < 4; ++r)
        PSW[((2 * ts + (mlan >> 3)) * 16 + 4 * qlan + r) * 8 + (mlan & 7)] =
            f2bf(accP[ts][r]);
  }
  bf16x8 ap[2];
#pragma unroll
  for (int sb = 0; sb < 2; ++sb)
    ap[sb] = ld128(SCR + w * 1024 + ((4 * sb + qlan) * 16 + mlan) * 8);

  f32x4 accY[4];
#pragma unroll
  for (int td = 0; td < 4; ++td) accY[td] = (f32x4){0.f, 0.f, 0.f, 0.f};

  // matmul2: Y += P V
#pragma unroll
  for (int td = 0; td < 4; ++td)
#pragma unroll
    for (int sb = 0; sb < 2; ++sb) {
      bf16x8 bv = ld128(VH + ((td * 2 + sb) * 64 + rslot) * 8);
      accY[td] = __builtin_amdgcn_mfma_f32_16x16x32_bf16(ap[sb], bv, accY[td], 0, 0, 0);
    }
  // matmul3: Y += Q * (Mhi + Mlo)
#pragma unroll
  for (int td = 0; td < 4; ++td)
#pragma unroll
    for (int kb = 0; kb < 2; ++kb) {
      bf16x8 bmh, bml;
      unpackM(mA[td * 2 + kb], mB[td * 2 + kb], bmh, bml);
      accY[td] = __builtin_amdgcn_mfma_f32_16x16x32_bf16(aq[kb], bmh, accY[td], 0, 0, 0);
      accY[td] = __builtin_amdgcn_mfma_f32_16x16x32_bf16(aq[kb], bml, accY[td], 0, 0, 0);
    }

#pragma unroll
  for (int td = 0; td < 4; ++td)
#pragma unroll
    for (int r = 0; r < 4; ++r)
      yp[base + (size_t)(16 * w + 4 * qlan + r) * SROW + 16 * td + mlan] = accY[td][r];
}

// ================= fallback: proven 3-kernel pipeline =================
__global__ __launch_bounds__(256) void k_chunksum(const float* __restrict__ kp,
                                                  const float* __restrict__ vp,
                                                  float* __restrict__ W) {
  const int bid = blockIdx.x;
  const int c   = bid % NC;
  const int bh  = bid / NC;
  const int b   = bh / H_, h = bh % H_;
  const size_t base = (size_t)b * SB + (size_t)h * D_ + (size_t)(c * CH) * SROW;

  __shared__ __align__(16) unsigned short KH[4096], KL[4096], VH[4096], VL[4096];

  const int tid = threadIdx.x;
  const int l = tid & 63, w = tid >> 6;
  const int mlan = l & 15, qlan = l >> 4;
  {
    const int t0 = (tid >> 4) * 4;
    const int m0 = tid & 15;
    const int qs = (t0 >> 3) & 3, kbs = t0 >> 5, j0 = t0 & 4;
    float4 kr[4], vr[4];
#pragma unroll
    for (int i = 0; i < 4; ++i) {
      const size_t g = base + (size_t)(t0 + i) * SROW + 4 * m0;
      kr[i] = *(const float4*)(kp + g);
      vr[i] = *(const float4*)(vp + g);
    }
#pragma unroll
    for (int r = 0; r < 4; ++r) {
      const int d = 4 * m0 + r;
      const int slot = r * 16 + qs * 4 + (m0 & 3);
      const int addr = (((d >> 4) * 2 + kbs) * 64 + slot) * 8 + j0;
      float ke[4] = { ((const float*)&kr[0])[r], ((const float*)&kr[1])[r],
                      ((const float*)&kr[2])[r], ((const float*)&kr[3])[r] };
      float ve[4] = { ((const float*)&vr[0])[r], ((const float*)&vr[1])[r],
                      ((const float*)&vr[2])[r], ((const float*)&vr[3])[r] };
      float kh[4], vh[4];
#pragma unroll
      for (int i = 0; i < 4; ++i) { kh[i] = bf2f(f2bf(ke[i])); vh[i] = bf2f(f2bf(ve[i])); }
      st4bf(KH + addr, kh[0], kh[1], kh[2], kh[3]);
      st4bf(KL + addr, ke[0] - kh[0], ke[1] - kh[1], ke[2] - kh[2], ke[3] - kh[3]);
      st4bf(VH + addr, vh[0], vh[1], vh[2], vh[3]);
      st4bf(VL + addr, ve[0] - vh[0], ve[1] - vh[1], ve[2] - vh[2], ve[3] - vh[3]);
    }
  }
  __syncthreads();

  const int rslot = ((mlan & 3) << 4) + (qlan << 2) + (mlan >> 2);
  bf16x8 avh[2], avl[2];
#pragma unroll
  for (int kb = 0; kb < 2; ++kb) {
    avh[kb] = ld128(VH + ((w * 2 + kb) * 64 + rslot) * 8);
    avl[kb] = ld128(VL + ((w * 2 + kb) * 64 + rslot) * 8);
  }
  float* Wc = W + (size_t)bid * (D_ * D_);
#pragma unroll
  for (int te = 0; te < 4; ++te) {
    f32x4 acc = {0.f, 0.f, 0.f, 0.f};
#pragma unroll
    for (int kb = 0; kb < 2; ++kb) {
      bf16x8 bkh = ld128(KH + ((te * 2 + kb) * 64 + rslot) * 8);
      bf16x8 bkl = ld128(KL + ((te * 2 + kb) * 64 + rslot) * 8);
      acc = __builtin_amdgcn_mfma_f32_16x16x32_bf16(avh[kb], bkh, acc, 0, 0, 0);
      acc = __builtin_amdgcn_mfma_f32_16x16x32_bf16(avl[kb], bkh, acc, 0, 0, 0);
      acc = __builtin_amdgcn_mfma_f32_16x16x32_bf16(avh[kb], bkl, acc, 0, 0, 0);
    }
#pragma unroll
    for (int r = 0; r < 4; ++r)
      Wc[(16 * w + 4 * qlan + r) * D_ + 16 * te + mlan] = acc[r];
  }
}

__global__ __launch_bounds__(256) void k_prefix(float* __restrict__ W) {
  const int g = blockIdx.x * 256 + threadIdx.x;
  float* base = W + (size_t)(g >> 12) * (NC * D_ * D_) + (g & 4095);
  float run = 0.f;
#pragma unroll
  for (int grp = 0; grp < 4; ++grp) {
    float v[16];
#pragma unroll
    for (int i = 0; i < 16; ++i)
      v[i] = base[(size_t)(grp * 16 + i) * (D_ * D_)];
#pragma unroll
    for (int i = 0; i < 16; ++i) {
      base[(size_t)(grp * 16 + i) * (D_ * D_)] = run;
      run += v[i];
    }
  }
}

__global__ __launch_bounds__(256) void k_output(const float* __restrict__ qp,
                                                const float* __restrict__ kp,
                                                const float* __restrict__ vp,
                                                const float* __restrict__ W,
                                                float* __restrict__ yp) {
  const int bid = blockIdx.x;
  const int c   = bid % NC;
  const int bh  = bid / NC;
  const int b   = bh / H_, h = bh % H_;
  const size_t base = (size_t)b * SB + (size_t)h * D_ + (size_t)(c * CH) * SROW;

  __shared__ __align__(16) unsigned short QF[4096], KF[4096], VF[4096],
                                          MH[4096], ML[4096], PS[64 * 72];

  const int tid = threadIdx.x;
  const int l = tid & 63, w = tid >> 6;
  const int mlan = l & 15, qlan = l >> 4;

#pragma unroll
  for (int it = 0; it < 4; ++it) {
    const int f = tid + it * 256;
    const int t = f >> 4, m0 = f & 15;
    const int kb = m0 >> 3, q = (m0 & 7) >> 1, j0 = (m0 & 1) * 4;
    const int addr = (((t >> 4) * 2 + kb) * 64 + ((t & 15) * 4 + q)) * 8 + j0;
    const size_t g = base + (size_t)t * SROW + 4 * m0;
    float4 qv = *(const float4*)(qp + g);
    float4 kv = *(const float4*)(kp + g);
    st4bf(QF + addr, qv.x, qv.y, qv.z, qv.w);
    st4bf(KF + addr, kv.x, kv.y, kv.z, kv.w);
    float4 mv = *(const float4*)(W + (size_t)bid * (D_ * D_) + t * D_ + 4 * m0);
    float mh[4] = { bf2f(f2bf(mv.x)), bf2f(f2bf(mv.y)), bf2f(f2bf(mv.z)), bf2f(f2bf(mv.w)) };
    st4bf(MH + addr, mh[0], mh[1], mh[2], mh[3]);
    st4bf(ML + addr, mv.x - mh[0], mv.y - mh[1], mv.z - mh[2], mv.w - mh[3]);
  }
  {
    const int s0 = (tid >> 4) * 4;
    const int m0 = tid & 15;
    const int qs = (s0 >> 3) & 3, kbs = s0 >> 5, j0 = s0 & 4;
    float4 vr[4];
#pragma unroll
    for (int i = 0; i < 4; ++i)
      vr[i] = *(const float4*)(vp + base + (size_t)(s0 + i) * SROW + 4 * m0);
#pragma unroll
    for (int r = 0; r < 4; ++r) {
      const int d = 4 * m0 + r;
      const int slot = r * 16 + qs * 4 + (m0 & 3);
      const int addr = (((d >> 4) * 2 + kbs) * 64 + slot) * 8 + j0;
      st4bf(VF + addr, ((const float*)&vr[0])[r], ((const float*)&vr[1])[r],
                       ((const float*)&vr[2])[r], ((const float*)&vr[3])[r]);
    }
  }
  __syncthreads();

  bf16x8 aq[2];
#pragma unroll
  for (int kb = 0; kb < 2; ++kb)
    aq[kb] = ld128(QF + ((w * 2 + kb) * 64 + (mlan * 4 + qlan)) * 8);

  f32x4 accP[4];
#pragma unroll
  for (int ts = 0; ts < 4; ++ts) accP[ts] = (f32x4){0.f, 0.f, 0.f, 0.f};
#pragma unroll
  for (int ts = 0; ts < 4; ++ts) {
    if (ts <= w) {
#pragma unroll
      for (int kb = 0; kb < 2; ++kb) {
        bf16x8 bk = ld128(KF + ((ts * 2 + kb) * 64 + (mlan * 4 + qlan)) * 8);
        accP[ts] = __builtin_amdgcn_mfma_f32_16x16x32_bf16(aq[kb], bk, accP[ts], 0, 0, 0);
      }
    }
  }
#pragma unroll
  for (int ts = 0; ts < 4; ++ts) {
    if (ts == w) {
#pragma unroll
      for (int r = 0; r < 4; ++r)
        if (mlan > qlan * 4 + r) accP[ts][r] = 0.f;
    }
  }
#pragma unroll
  for (int ts = 0; ts < 4; ++ts)
#pragma unroll
    for (int r = 0; r < 4; ++r)
      PS[(16 * w + 4 * qlan + r) * 72 + 16 * ts + mlan] = f2bf(accP[ts][r]);

  bf16x8 ap[2];
#pragma unroll
  for (int sb = 0; sb < 2; ++sb)
    ap[sb] = ld128(PS + (16 * w + mlan) * 72 + 32 * sb + 8 * qlan);

  const int rslot = ((mlan & 3) << 4) + (qlan << 2) + (mlan >> 2);

  f32x4 accY[4];
#pragma unroll
  for (int td = 0; td < 4; ++td) accY[td] = (f32x4){0.f, 0.f, 0.f, 0.f};

#pragma unroll
  for (int td = 0; td < 4; ++td)
#pragma unroll
    for (int sb = 0; sb < 2; ++sb) {
      bf16x8 bv = ld128(VF + ((td * 2 + sb) * 64 + rslot) * 8);
      accY[td] = __builtin_amdgcn_mfma_f32_16x16x32_bf16(ap[sb], bv, accY[td], 0, 0, 0);
    }
#pragma unroll
  for (int td = 0; td < 4; ++td)
#pragma unroll
    for (int kb = 0; kb < 2; ++kb) {
      bf16x8 bmh = ld128(MH + ((td * 2 + kb) * 64 + (mlan * 4 + qlan)) * 8);
      accY[td] = __builtin_amdgcn_mfma_f32_16x16x32_bf16(aq[kb], bmh, accY[td], 0, 0, 0);
      bf16x8 bml = ld128(ML + ((td * 2 + kb) * 64 + (mlan * 4 + qlan)) * 8);
      accY[td] = __builtin_amdgcn_mfma_f32_16x16x32_bf16(aq[kb], bml, accY[td], 0, 0, 0);
    }

#pragma unroll
  for (int td = 0; td < 4; ++td)
#pragma unroll
    for (int r = 0; r < 4; ++r)
      yp[base + (size_t)(16 * w + 4 * qlan + r) * SROW + 16 * td + mlan] = accY[td][r];
}

extern "C" void kernel_launch(void* const* d_in, const int* in_sizes, int n_in,
                              void* d_out, int out_size, void* d_ws, size_t ws_size,
                              hipStream_t stream) {
  const float* q = (const float*)d_in[0];
  const float* k = (const float*)d_in[1];
  const float* v = (const float*)d_in[2];
  float* y = (float*)d_out;
  float* W = (float*)d_ws;  // 16.78 MB used

  void* args[] = { (void*)&q, (void*)&k, (void*)&v, (void*)&W, (void*)&y };
  hipError_t err = hipLaunchCooperativeKernel((const void*)k_fused,
                                              dim3(BH * NC), dim3(256),
                                              args, 0, stream);
  if (err != hipSuccess) {
    (void)hipGetLastError();  // clear error state
    k_chunksum<<<BH * NC, 256, 0, stream>>>(k, v, W);
    k_prefix  <<<256, 256, 0, stream>>>(W);
    k_output  <<<BH * NC, 256, 0, stream>>>(q, k, v, W, y);
  }
}

// Round 6
// 110.775 us; speedup vs baseline: 6.4520x; 6.4520x over previous
//
#include <hip/hip_runtime.h>

// LinearMemoryBackend: y_t = M_t q_t, M_t = sum_{s<=t} v_s k_s^T
// Chunked (C=64), MFMA bf16, 3-kernel pipeline (grid.sync proven toxic on r5):
//  k1: S_c[d][e] = sum_t v[t,d] k[t,e]  (pure bf16 MFMA, S stored bf16)
//  k2: exclusive prefix over chunks (fp32 accum; M stored packed bf16 hi|lo u32)
//  k3: y = (QK^T masked)V + Q*(Mhi+Mlo)   (M B-frags straight from global)
// ws: S bf16 at offset 0 (8.4 MB), M packed u32 at offset 32 MB (16.8 MB).

#define B_   2
#define T_   4096
#define H_   8
#define D_   64
#define CH   64
#define NC   (T_ / CH)
#define BH   (B_ * H_)
#define SROW (H_ * D_)
#define SB   (T_ * H_ * D_)

typedef __attribute__((ext_vector_type(4))) float f32x4;
typedef __attribute__((ext_vector_type(8))) short bf16x8;

__device__ inline unsigned short f2bf(float f) {
  unsigned int u = __builtin_bit_cast(unsigned int, f);
  unsigned int r = (u + 0x7FFFu + ((u >> 16) & 1u)) >> 16;
  return (unsigned short)r;
}
__device__ inline float bf2f(unsigned short b) {
  unsigned int u = ((unsigned int)b) << 16;
  return __builtin_bit_cast(float, u);
}
__device__ inline void st4bf(unsigned short* p, float a, float b, float c, float d) {
  union { uint2 u; unsigned short s[4]; } x;
  x.s[0] = f2bf(a); x.s[1] = f2bf(b); x.s[2] = f2bf(c); x.s[3] = f2bf(d);
  *(uint2*)p = x.u;
}
__device__ inline bf16x8 ld128(const unsigned short* p) {
  union { uint4 u; bf16x8 v; } x;
  x.u = *(const uint4*)p;
  return x.v;
}
// unpack 8 consecutive packed (hi<<16|lo) u32 into hi/lo bf16x8 B-frags (r5-validated)
__device__ inline void unpackM(const uint4 a, const uint4 b, bf16x8& hi, bf16x8& lo) {
  unsigned xs[8] = { a.x, a.y, a.z, a.w, b.x, b.y, b.z, b.w };
  union { unsigned u[4]; bf16x8 v; } H, L;
#pragma unroll
  for (int i = 0; i < 4; ++i) {
    unsigned p0 = xs[2 * i], p1 = xs[2 * i + 1];
    H.u[i] = (p0 >> 16) | (p1 & 0xffff0000u);
    L.u[i] = (p0 & 0xffffu) | (p1 << 16);
  }
  hi = H.v; lo = L.v;
}

// fragment slot orderings (lane l: m = l&15, q = l>>4)
//  row-access operands: slot_A = m*4+q
//  transpose-staged:    slot_V = (m&3)*16 + q*4 + (m>>2)

// ---------------- kernel 1: chunk outer-product sums (pure bf16) ----------------
__global__ __launch_bounds__(256) void k_chunksum(const float* __restrict__ kp,
                                                  const float* __restrict__ vp,
                                                  unsigned short* __restrict__ Sp) {
  const int bid = blockIdx.x;
  const int c   = bid & 63;
  const int bh  = bid >> 6;
  const int b   = bh >> 3, h = bh & 7;
  const size_t base = (size_t)b * SB + (size_t)h * D_ + (size_t)(c * CH) * SROW;

  __shared__ __align__(16) unsigned short KT[4096], VT[4096];

  const int tid = threadIdx.x;
  const int l = tid & 63, w = tid >> 6;
  const int mlan = l & 15, qlan = l >> 4;

  // transposed bf16 staging (4x4 register transpose)
  {
    const int t0 = (tid >> 4) * 4;
    const int m0 = tid & 15;
    const int qs = (t0 >> 3) & 3, kbs = t0 >> 5, j0 = t0 & 4;
    float4 kr[4], vr[4];
#pragma unroll
    for (int i = 0; i < 4; ++i) {
      const size_t g = base + (size_t)(t0 + i) * SROW + 4 * m0;
      kr[i] = *(const float4*)(kp + g);
      vr[i] = *(const float4*)(vp + g);
    }
#pragma unroll
    for (int r = 0; r < 4; ++r) {
      const int d = 4 * m0 + r;
      const int slot = r * 16 + qs * 4 + (m0 & 3);
      const int addr = (((d >> 4) * 2 + kbs) * 64 + slot) * 8 + j0;
      st4bf(KT + addr, ((const float*)&kr[0])[r], ((const float*)&kr[1])[r],
                       ((const float*)&kr[2])[r], ((const float*)&kr[3])[r]);
      st4bf(VT + addr, ((const float*)&vr[0])[r], ((const float*)&vr[1])[r],
                       ((const float*)&vr[2])[r], ((const float*)&vr[3])[r]);
    }
  }
  __syncthreads();

  const int rslot = ((mlan & 3) << 4) + (qlan << 2) + (mlan >> 2);
  bf16x8 av[2];
  av[0] = ld128(VT + ((w * 2 + 0) * 64 + rslot) * 8);
  av[1] = ld128(VT + ((w * 2 + 1) * 64 + rslot) * 8);

  unsigned short* Sc = Sp + (size_t)bid * 4096;
#pragma unroll
  for (int te = 0; te < 4; ++te) {
    f32x4 acc = {0.f, 0.f, 0.f, 0.f};
#pragma unroll
    for (int kb = 0; kb < 2; ++kb) {
      bf16x8 bk = ld128(KT + ((te * 2 + kb) * 64 + rslot) * 8);
      acc = __builtin_amdgcn_mfma_f32_16x16x32_bf16(av[kb], bk, acc, 0, 0, 0);
    }
#pragma unroll
    for (int r = 0; r < 4; ++r)
      Sc[(16 * w + 4 * qlan + r) * 64 + 16 * te + mlan] = f2bf(acc[r]);
  }
}

// ---------------- kernel 2: exclusive prefix (bf16 S in, packed hi|lo M out) ----------------
// 65536 threads = 256 blocks (all CUs); one column per thread; 16-deep load batches.
__global__ __launch_bounds__(256) void k_prefix(const unsigned short* __restrict__ Sp,
                                                unsigned* __restrict__ Mp) {
  const int g = blockIdx.x * 256 + threadIdx.x;   // 0..65535
  const int bh = g >> 12, e = g & 4095;
  const unsigned short* sp = Sp + (size_t)bh * (NC * 4096) + e;
  unsigned* mp = Mp + (size_t)bh * (NC * 4096) + e;
  float run = 0.f;
#pragma unroll
  for (int grp = 0; grp < 4; ++grp) {
    unsigned short sv[16];
#pragma unroll
    for (int i = 0; i < 16; ++i)
      sv[i] = sp[(size_t)(grp * 16 + i) * 4096];
#pragma unroll
    for (int i = 0; i < 16; ++i) {
      const unsigned short hi = f2bf(run);
      const unsigned short lo = f2bf(run - bf2f(hi));
      mp[(size_t)(grp * 16 + i) * 4096] = ((unsigned)hi << 16) | (unsigned)lo;
      run += bf2f(sv[i]);
    }
  }
}

// ---------------- kernel 3: y = (QK^T masked)V + Q*M ----------------
__global__ __launch_bounds__(256) void k_output(const float* __restrict__ qp,
                                                const float* __restrict__ kp,
                                                const float* __restrict__ vp,
                                                const unsigned* __restrict__ Mp,
                                                float* __restrict__ yp) {
  const int bid = blockIdx.x;
  const int c   = bid & 63;
  const int bh  = bid >> 6;
  const int b   = bh >> 3, h = bh & 7;
  const size_t base = (size_t)b * SB + (size_t)h * D_ + (size_t)(c * CH) * SROW;

  // 32 KB total -> 4 blocks/CU
  __shared__ __align__(16) unsigned short QF[4096], KF[4096], VF[4096], PS[4096];

  const int tid = threadIdx.x;
  const int l = tid & 63, w = tid >> 6;
  const int mlan = l & 15, qlan = l >> 4;

  // prefetch M B-frags (packed u32) early — 16 dwordx4 in flight
  uint4 mA[8], mB[8];
#pragma unroll
  for (int td = 0; td < 4; ++td)
#pragma unroll
    for (int kb = 0; kb < 2; ++kb) {
      const uint4* mp = (const uint4*)(Mp + (size_t)bid * 4096
                                      + (16 * td + mlan) * 64 + 32 * kb + 8 * qlan);
      mA[td * 2 + kb] = mp[0];
      mB[td * 2 + kb] = mp[1];
    }

  // stage Q,K row-form (A/B-frag order)
#pragma unroll
  for (int it = 0; it < 4; ++it) {
    const int f = tid + it * 256;
    const int t = f >> 4, m0 = f & 15;
    const int kb = m0 >> 3, qq = (m0 & 7) >> 1, j0 = (m0 & 1) * 4;
    const int addr = (((t >> 4) * 2 + kb) * 64 + ((t & 15) * 4 + qq)) * 8 + j0;
    const size_t g = base + (size_t)t * SROW + 4 * m0;
    float4 qv = *(const float4*)(qp + g);
    float4 kv = *(const float4*)(kp + g);
    st4bf(QF + addr, qv.x, qv.y, qv.z, qv.w);
    st4bf(KF + addr, kv.x, kv.y, kv.z, kv.w);
  }
  // stage V transposed
  {
    const int s0 = (tid >> 4) * 4;
    const int m0 = tid & 15;
    const int qs = (s0 >> 3) & 3, kbs = s0 >> 5, j0 = s0 & 4;
    float4 vr[4];
#pragma unroll
    for (int i = 0; i < 4; ++i)
      vr[i] = *(const float4*)(vp + base + (size_t)(s0 + i) * SROW + 4 * m0);
#pragma unroll
    for (int r = 0; r < 4; ++r) {
      const int d = 4 * m0 + r;
      const int slot = r * 16 + qs * 4 + (m0 & 3);
      const int addr = (((d >> 4) * 2 + kbs) * 64 + slot) * 8 + j0;
      st4bf(VF + addr, ((const float*)&vr[0])[r], ((const float*)&vr[1])[r],
                       ((const float*)&vr[2])[r], ((const float*)&vr[3])[r]);
    }
  }
  __syncthreads();

  bf16x8 aq[2];
#pragma unroll
  for (int kb = 0; kb < 2; ++kb)
    aq[kb] = ld128(QF + ((w * 2 + kb) * 64 + (mlan * 4 + qlan)) * 8);

  // matmul1: P = Q K^T (causal tiles only)
  f32x4 accP[4];
#pragma unroll
  for (int ts = 0; ts < 4; ++ts) accP[ts] = (f32x4){0.f, 0.f, 0.f, 0.f};
#pragma unroll
  for (int ts = 0; ts < 4; ++ts) {
    if (ts <= w) {
#pragma unroll
      for (int kb = 0; kb < 2; ++kb) {
        bf16x8 bk = ld128(KF + ((ts * 2 + kb) * 64 + (mlan * 4 + qlan)) * 8);
        accP[ts] = __builtin_amdgcn_mfma_f32_16x16x32_bf16(aq[kb], bk, accP[ts], 0, 0, 0);
      }
    }
  }
  // diagonal mask (keep s<=t)
#pragma unroll
  for (int ts = 0; ts < 4; ++ts)
    if (ts == w) {
#pragma unroll
      for (int r = 0; r < 4; ++r)
        if (mlan > qlan * 4 + r) accP[ts][r] = 0.f;
    }

  // P strip -> PS, octet layout (wave-private 1024-short region, r5-validated)
  {
    unsigned short* PSW = PS + w * 1024;
#pragma unroll
    for (int ts = 0; ts < 4; ++ts)
#pragma unroll
      for (int r = 0; r < 4; ++r)
        PSW[((2 * ts + (mlan >> 3)) * 16 + 4 * qlan + r) * 8 + (mlan & 7)] =
            f2bf(accP[ts][r]);
  }
  bf16x8 ap[2];
#pragma unroll
  for (int sb = 0; sb < 2; ++sb)
    ap[sb] = ld128(PS + w * 1024 + ((4 * sb + qlan) * 16 + mlan) * 8);

  const int rslot = ((mlan & 3) << 4) + (qlan << 2) + (mlan >> 2);

  f32x4 accY[4];
#pragma unroll
  for (int td = 0; td < 4; ++td) accY[td] = (f32x4){0.f, 0.f, 0.f, 0.f};

  // matmul2: Y += P V
#pragma unroll
  for (int td = 0; td < 4; ++td)
#pragma unroll
    for (int sb = 0; sb < 2; ++sb) {
      bf16x8 bv = ld128(VF + ((td * 2 + sb) * 64 + rslot) * 8);
      accY[td] = __builtin_amdgcn_mfma_f32_16x16x32_bf16(ap[sb], bv, accY[td], 0, 0, 0);
    }
  // matmul3: Y += Q * (Mhi + Mlo)
#pragma unroll
  for (int td = 0; td < 4; ++td)
#pragma unroll
    for (int kb = 0; kb < 2; ++kb) {
      bf16x8 bmh, bml;
      unpackM(mA[td * 2 + kb], mB[td * 2 + kb], bmh, bml);
      accY[td] = __builtin_amdgcn_mfma_f32_16x16x32_bf16(aq[kb], bmh, accY[td], 0, 0, 0);
      accY[td] = __builtin_amdgcn_mfma_f32_16x16x32_bf16(aq[kb], bml, accY[td], 0, 0, 0);
    }

#pragma unroll
  for (int td = 0; td < 4; ++td)
#pragma unroll
    for (int r = 0; r < 4; ++r)
      yp[base + (size_t)(16 * w + 4 * qlan + r) * SROW + 16 * td + mlan] = accY[td][r];
}

extern "C" void kernel_launch(void* const* d_in, const int* in_sizes, int n_in,
                              void* d_out, int out_size, void* d_ws, size_t ws_size,
                              hipStream_t stream) {
  const float* q = (const float*)d_in[0];
  const float* k = (const float*)d_in[1];
  const float* v = (const float*)d_in[2];
  float* y = (float*)d_out;
  unsigned short* S = (unsigned short*)d_ws;                       // 8.4 MB bf16
  unsigned*       M = (unsigned*)((char*)d_ws + (32u << 20));      // 16.8 MB packed u32

  k_chunksum<<<BH * NC, 256, 0, stream>>>(k, v, S);
  k_prefix  <<<256, 256, 0, stream>>>(S, M);
  k_output  <<<BH * NC, 256, 0, stream>>>(q, k, v, M, y);
}